// Round 5
// baseline (420.647 us; speedup 1.0000x reference)
//
#include <hip/hip_runtime.h>
#include <stdint.h>

// NNCLR forward on MI355X — round 5.
// Changes vs round 4:
//  * k2: TRANSPOSED MFMA (Q·Pᵀ): reduction dim (queue col n) is in-lane in the C layout,
//    so the per-row argmax epilogue is 7 v_max + 2 shfl per (m, 32-group) instead of
//    8 u64-shfls per group (round-4's 167 µs was this shuffle storm on the LDS pipe).
//  * cand is value-only float[g][m] (8 MB, coalesced stores) — fp32 rescore re-derives the
//    column, so the bf16 argmax col (and its min-col shfl reduce) is dead weight.
//  * k2b/k2c/k2e merged into k2bc (16 blocks, coalesced scans); nnidx folded into k3.
//    9 kernels -> 6.
//
// Numerical safety unchanged: group containing fp32-argmax col has bf16 groupmax >=
// rowmax_bf16 - 2e, 2e = 7.8e-3 < MARGIN = 0.01 => always rescored; argmax decided in fp32.

#define BATCH  512
#define DIM    256
#define QUEUE  65536
#define MROWS  1024
#define NGRP   2048          // 65536 / 32
#define MARGIN 0.01f

typedef short bf16x8 __attribute__((ext_vector_type(8)));
typedef float f32x4  __attribute__((ext_vector_type(4)));

__device__ __forceinline__ unsigned int mono_f32(float f) {
    unsigned int u = __float_as_uint(f);
    return (u & 0x80000000u) ? ~u : (u | 0x80000000u);
}
__device__ __forceinline__ unsigned short f2bf(float f) {   // RNE fp32->bf16
    unsigned int u = __float_as_uint(f);
    return (unsigned short)((u + 0x7fffu + ((u >> 16) & 1u)) >> 16);
}

// ---------------- k1: normalize ----------------
__global__ void k1_norm(const float* __restrict__ p1, const float* __restrict__ p2,
                        float* __restrict__ Pn, float* __restrict__ PnT,
                        unsigned short* __restrict__ Phi, float* __restrict__ outq,
                        int* __restrict__ npairs)
{
    const int r = blockIdx.x;        // 0..1023
    const int t = threadIdx.x;       // 0..63
    if (r == 0 && t == 0) *npairs = 0;
    const float* src = (r < BATCH) ? p1 : p2;
    const int row = (r < BATCH) ? r : r - BATCH;
    float4 v = ((const float4*)(src + (size_t)row * DIM))[t];
    float sq = v.x*v.x + v.y*v.y + v.z*v.z + v.w*v.w;
    #pragma unroll
    for (int off = 32; off; off >>= 1) sq += __shfl_xor(sq, off, 64);
    sq = fmaxf(sq, 1e-12f);
    float s = rsqrtf(sq);
    s = s * (1.5f - 0.5f * sq * s * s);
    v.x *= s; v.y *= s; v.z *= s; v.w *= s;
    ((float4*)(Pn + (size_t)r * DIM))[t] = v;
    const int k = t * 4;
    PnT[(size_t)(k + 0) * MROWS + r] = v.x;
    PnT[(size_t)(k + 1) * MROWS + r] = v.y;
    PnT[(size_t)(k + 2) * MROWS + r] = v.z;
    PnT[(size_t)(k + 3) * MROWS + r] = v.w;
    short4 b;
    b.x = (short)f2bf(v.x); b.y = (short)f2bf(v.y);
    b.z = (short)f2bf(v.z); b.w = (short)f2bf(v.w);
    ((short4*)Phi)[(size_t)r * (DIM / 4) + t] = b;
    if (r < BATCH) ((float4*)(outq + (size_t)r * DIM))[t] = v;  // new_queue[0:512] = p1n
}

// ---------------- k2: transposed bf16 MFMA filter + fused convert + FIFO copy ----------------
// 512 blocks, one per 128-row queue tile. LDS: Q-tile, 16B chunk (r, c16) at
// r*512 + ((c16 ^ (r & 31)) << 4). mfma(Qfrag, Pfrag): C rows = n (q*4+reg), C cols = m (lr).
__global__ __launch_bounds__(256, 2)
void k2_mfma(const unsigned short* __restrict__ Phi, const float* __restrict__ queue,
             float* __restrict__ outq, float* __restrict__ cand)
{
    __shared__ __align__(16) char Bs[65536];
    const int nt = blockIdx.x;       // 0..511
    const int n0 = nt * 128;
    const int t  = threadIdx.x;
    const int w  = t >> 6, lane = t & 63;
    const int wm = w & 1, wn = w >> 1;
    const int lr = lane & 15, q = lane >> 4;

    // ---- stage: read queue fp32 tile (coalesced), FIFO-copy to outq, cvt bf16 -> swizzled LDS
    {
        const float4* qsrc = (const float4*)(queue + (size_t)n0 * DIM);
        float4* qdst = (float4*)(outq + (size_t)(n0 + BATCH) * DIM);
        #pragma unroll 4
        for (int it = 0; it < 32; ++it) {
            const int L = it * 256 + t;          // 0..8191
            const int r = L >> 6, h = L & 63;
            float4 v = qsrc[(size_t)r * 64 + h];
            if (n0 + r < QUEUE - BATCH) qdst[(size_t)r * 64 + h] = v;
            short4 b;
            b.x = (short)f2bf(v.x); b.y = (short)f2bf(v.y);
            b.z = (short)f2bf(v.z); b.w = (short)f2bf(v.w);
            const int c16 = h >> 1, half = h & 1;
            *(short4*)(Bs + r * 512 + ((c16 ^ (r & 31)) << 4) + half * 8) = b;
        }
    }
    __syncthreads();

    const unsigned short* Pw = Phi + (size_t)(wm * 64 + lr) * DIM + q * 8;

    for (int mt = 0; mt < 8; ++mt) {
        const int m0 = mt * 128;
        f32x4 acc[4][4];                 // [ni][mj]
        #pragma unroll
        for (int i = 0; i < 4; ++i)
            #pragma unroll
            for (int j = 0; j < 4; ++j) acc[i][j] = (f32x4){0.f, 0.f, 0.f, 0.f};

        const unsigned short* Pmt = Pw + (size_t)m0 * DIM;
        #pragma unroll 2
        for (int ks = 0; ks < 8; ++ks) {
            bf16x8 qf[4], pf[4];
            #pragma unroll
            for (int ni = 0; ni < 4; ++ni) {
                const int r = wn * 64 + ni * 16 + lr;
                const int c16 = ks * 4 + q;
                qf[ni] = *(const bf16x8*)(Bs + r * 512 + ((c16 ^ (r & 31)) << 4));
            }
            #pragma unroll
            for (int mj = 0; mj < 4; ++mj)
                pf[mj] = *(const bf16x8*)(Pmt + (size_t)mj * 16 * DIM + ks * 32);
            #pragma unroll
            for (int ni = 0; ni < 4; ++ni)
                #pragma unroll
                for (int mj = 0; mj < 4; ++mj)
                    acc[ni][mj] = __builtin_amdgcn_mfma_f32_16x16x32_bf16(qf[ni], pf[mj], acc[ni][mj], 0, 0, 0);
        }

        // ---- epilogue: per (m, 32-n-group) max. n = wn*64 + ni*16 + q*4 + reg (in-lane+q),
        //      m = m0 + wm*64 + mj*16 + lr (across 16 lanes -> coalesced 64B stores).
        #pragma unroll
        for (int mj = 0; mj < 4; ++mj) {
            #pragma unroll
            for (int gl = 0; gl < 2; ++gl) {
                f32x4 va = acc[2 * gl][mj], vb = acc[2 * gl + 1][mj];
                float mx = fmaxf(fmaxf(fmaxf(va[0], va[1]), fmaxf(va[2], va[3])),
                                 fmaxf(fmaxf(vb[0], vb[1]), fmaxf(vb[2], vb[3])));
                mx = fmaxf(mx, __shfl_xor(mx, 16, 64));
                mx = fmaxf(mx, __shfl_xor(mx, 32, 64));
                if (q == 0)
                    cand[(size_t)(nt * 4 + wn * 2 + gl) * MROWS + (m0 + wm * 64 + mj * 16 + lr)] = mx;
            }
        }
    }
}

// ---------------- k2bc: rowmax + margin filter + pair list (16 blocks) ----------------
__global__ void k2bc(const float* __restrict__ cand,
                     unsigned long long* __restrict__ rowfinal,
                     unsigned int* __restrict__ pairs, int* __restrict__ npairs)
{
    const int t = threadIdx.x;               // 256
    const int ml = t & 63, gs = t >> 6;      // 4 g-slices of 512
    const int m = blockIdx.x * 64 + ml;      // 16 blocks x 64 m
    __shared__ float pm[4][64];
    float mx = -1e30f;
    for (int g = gs * 512; g < gs * 512 + 512; ++g)
        mx = fmaxf(mx, cand[(size_t)g * MROWS + m]);
    pm[gs][ml] = mx;
    __syncthreads();
    const float rm = fmaxf(fmaxf(pm[0][ml], pm[1][ml]), fmaxf(pm[2][ml], pm[3][ml]));
    const float thr = rm - MARGIN;
    if (gs == 0) rowfinal[m] = 0ull;         // ws re-poisoned 0xAA every call
    for (int g = gs * 512; g < gs * 512 + 512; ++g)
        if (cand[(size_t)g * MROWS + m] >= thr) {
            int p = atomicAdd(npairs, 1);
            pairs[p] = ((unsigned int)m << 16) | (unsigned int)g;
        }
}

// ---------------- k2d: exact fp32 rescore, one wave per (row,group) ----------------
__global__ __launch_bounds__(256, 4)
void k2d_rescore(const unsigned int* __restrict__ pairs, const int* __restrict__ npairs,
                 const float* __restrict__ Pn, const float* __restrict__ queue,
                 unsigned long long* __restrict__ rowfinal)
{
    const int t = threadIdx.x, w = t >> 6, lane = t & 63;
    const int n = *npairs;
    const int col_l = lane & 31, half = lane >> 5;
    for (int p = blockIdx.x * 4 + w; p < n; p += gridDim.x * 4) {
        const unsigned int pr = pairs[p];
        const int row = pr >> 16, g = pr & 0xffff;
        const int col = g * 32 + col_l;
        const float4* qp = (const float4*)(queue + (size_t)col * DIM + half * 128);
        const float4* pp = (const float4*)(Pn + (size_t)row * DIM + half * 128);
        float4 sv = {0.f, 0.f, 0.f, 0.f};
        #pragma unroll 8
        for (int j = 0; j < 32; ++j) {
            float4 a = pp[j], b = qp[j];
            sv.x = fmaf(a.x, b.x, sv.x); sv.y = fmaf(a.y, b.y, sv.y);
            sv.z = fmaf(a.z, b.z, sv.z); sv.w = fmaf(a.w, b.w, sv.w);
        }
        float s = (sv.x + sv.y) + (sv.z + sv.w);
        s += __shfl_xor(s, 32, 64);                       // combine k-halves
        unsigned long long best = ((unsigned long long)mono_f32(s) << 32)
                                | (unsigned int)(65535 - col);
        #pragma unroll
        for (int off = 1; off <= 16; off <<= 1) {
            unsigned long long o = __shfl_xor(best, off, 64);
            best = best > o ? best : o;
        }
        if (lane == 0) atomicMax(rowfinal + row, best);
    }
}

// ---------------- k3: S1/S2 similarity matrices (8 rows/block, nnidx from rowfinal) --------
__global__ void k3_sim(const unsigned long long* __restrict__ rowfinal,
                       const float* __restrict__ queue,
                       const float* __restrict__ PnT, float* __restrict__ S)
{
    const int rb = blockIdx.x * 8;   // 0..1016 (rows of [nn1;nn2])
    const int tid = threadIdx.x;     // 256
    const int which = (rb < BATCH) ? 0 : 1;
    const int colbase = which ? 0 : BATCH;    // S1 vs p2 (cols 512..1023), S2 vs p1 (0..511)
    __shared__ float nnv[8][DIM];
    #pragma unroll
    for (int j = 0; j < 8; ++j) {
        const int idx = 65535 - (int)(rowfinal[rb + j] & 0xFFFFull);
        nnv[j][tid] = queue[(size_t)idx * DIM + tid];
    }
    __syncthreads();
    float acc0[8], acc1[8];
    #pragma unroll
    for (int j = 0; j < 8; ++j) { acc0[j] = 0.f; acc1[j] = 0.f; }
    for (int k4 = 0; k4 < 64; ++k4) {
        float4 nv[8];
        #pragma unroll
        for (int j = 0; j < 8; ++j) nv[j] = ((const float4*)nnv[j])[k4];
        #pragma unroll
        for (int kk = 0; kk < 4; ++kk) {
            const int k = k4 * 4 + kk;
            const float v0 = PnT[(size_t)k * MROWS + colbase + tid];
            const float v1 = PnT[(size_t)k * MROWS + colbase + tid + 256];
            #pragma unroll
            for (int j = 0; j < 8; ++j) {
                const float nj = ((const float*)&nv[j])[kk];
                acc0[j] = fmaf(nj, v0, acc0[j]);
                acc1[j] = fmaf(nj, v1, acc1[j]);
            }
        }
    }
    const int i0 = rb & (BATCH - 1);
    float* Sout = S + (size_t)which * (BATCH * BATCH);
    #pragma unroll
    for (int j = 0; j < 8; ++j) {
        Sout[(size_t)(i0 + j) * BATCH + tid]       = acc0[j] * 10.0f;
        Sout[(size_t)(i0 + j) * BATCH + tid + 256] = acc1[j] * 10.0f;
    }
}

// ---------------- k4: loss ----------------
__global__ void k4_loss(const float* __restrict__ S, float* __restrict__ loss)
{
    const int r = blockIdx.x;        // 0..2047
    const int tid = threadIdx.x;     // 256
    const int grp = r >> 9;
    const int i = r & 511;
    const float* M = S + (size_t)(grp >> 1) * (BATCH * BATCH);
    float x0, x1;
    if (!(grp & 1)) { x0 = M[(size_t)i * BATCH + tid];  x1 = M[(size_t)i * BATCH + tid + 256]; }
    else            { x0 = M[(size_t)tid * BATCH + i];  x1 = M[(size_t)(tid + 256) * BATCH + i]; }
    const float diag = M[(size_t)i * BATCH + i];
    float mx = fmaxf(x0, x1);
    #pragma unroll
    for (int off = 1; off < 64; off <<= 1) mx = fmaxf(mx, __shfl_xor(mx, off, 64));
    __shared__ float redm[4], reds[4];
    if ((tid & 63) == 0) redm[tid >> 6] = mx;
    __syncthreads();
    mx = fmaxf(fmaxf(redm[0], redm[1]), fmaxf(redm[2], redm[3]));
    float e = __expf(x0 - mx) + __expf(x1 - mx);
    #pragma unroll
    for (int off = 1; off < 64; off <<= 1) e += __shfl_xor(e, off, 64);
    if ((tid & 63) == 0) reds[tid >> 6] = e;
    __syncthreads();
    if (tid == 0)
        loss[r] = mx + logf(reds[0] + reds[1] + reds[2] + reds[3]) - diag;
}

// ---------------- launcher ----------------
extern "C" void kernel_launch(void* const* d_in, const int* in_sizes, int n_in,
                              void* d_out, int out_size, void* d_ws, size_t ws_size,
                              hipStream_t stream)
{
    const float* p1    = (const float*)d_in[0];
    const float* p2    = (const float*)d_in[1];
    const float* queue = (const float*)d_in[2];
    float* out  = (float*)d_out;
    float* loss = out;
    float* outq = out + 4 * BATCH;

    // Workspace (~20.6 MB)
    char* w = (char*)d_ws;
    float* cand = (float*)w;                               w += (size_t)NGRP * MROWS * 4;   // 8 MB [g][m]
    unsigned long long* rowfinal = (unsigned long long*)w; w += MROWS * 8;
    float* Pn  = (float*)w;                                w += (size_t)MROWS * DIM * 4;    // 1 MB
    float* PnT = (float*)w;                                w += (size_t)MROWS * DIM * 4;    // 1 MB
    unsigned short* Phi = (unsigned short*)w;              w += (size_t)MROWS * DIM * 2;    // 0.5 MB
    float* S = (float*)w;                                  w += (size_t)2 * BATCH * BATCH * 4; // 2 MB
    unsigned int* pairs = (unsigned int*)w;                w += (size_t)NGRP * MROWS * 4;   // 8 MB (worst case)
    int* npairs = (int*)w;

    hipLaunchKernelGGL(k1_norm,     dim3(MROWS), dim3(64),  0, stream, p1, p2, Pn, PnT, Phi, outq, npairs);
    hipLaunchKernelGGL(k2_mfma,     dim3(QUEUE / 128), dim3(256), 0, stream, Phi, queue, outq, cand);
    hipLaunchKernelGGL(k2bc,        dim3(16),    dim3(256), 0, stream, cand, rowfinal, pairs, npairs);
    hipLaunchKernelGGL(k2d_rescore, dim3(512),   dim3(256), 0, stream, pairs, npairs, Pn, queue, rowfinal);
    hipLaunchKernelGGL(k3_sim,      dim3(MROWS / 8), dim3(256), 0, stream, rowfinal, queue, PnT, S);
    hipLaunchKernelGGL(k4_loss,     dim3(4 * BATCH), dim3(256), 0, stream, S, loss);
}

// Round 6
// 292.832 us; speedup vs baseline: 1.4365x; 1.4365x over previous
//
#include <hip/hip_runtime.h>
#include <stdint.h>

// NNCLR forward on MI355X — round 6.
// Changes vs round 5:
//  * round-5's merged k2bc (16 blocks) was a serial-latency scan: 164 µs at 0.7% occupancy.
//    Split into k2b_rowmax + k2c_filter, 256 blocks each, unrolled g-scans (8 loads in
//    flight), atomicMax(mono) rowmax. Predicted 164 -> ~5-10 µs combined.
//  * rowmaxU / rowfinal / npairs init moved into k1 (ws re-poisoned 0xAA every call).
//  * k2_mfma / k2d / k3 / k4 unchanged from round 5 (passed, absmax 0).

#define BATCH  512
#define DIM    256
#define QUEUE  65536
#define MROWS  1024
#define NGRP   2048          // 65536 / 32
#define MARGIN 0.01f

typedef short bf16x8 __attribute__((ext_vector_type(8)));
typedef float f32x4  __attribute__((ext_vector_type(4)));

__device__ __forceinline__ unsigned int mono_f32(float f) {
    unsigned int u = __float_as_uint(f);
    return (u & 0x80000000u) ? ~u : (u | 0x80000000u);
}
__device__ __forceinline__ float unmono_f32(unsigned int m) {
    unsigned int u = (m & 0x80000000u) ? (m ^ 0x80000000u) : ~m;
    return __uint_as_float(u);
}
__device__ __forceinline__ unsigned short f2bf(float f) {   // RNE fp32->bf16
    unsigned int u = __float_as_uint(f);
    return (unsigned short)((u + 0x7fffu + ((u >> 16) & 1u)) >> 16);
}

// ---------------- k1: normalize + ws init ----------------
__global__ void k1_norm(const float* __restrict__ p1, const float* __restrict__ p2,
                        float* __restrict__ Pn, float* __restrict__ PnT,
                        unsigned short* __restrict__ Phi, float* __restrict__ outq,
                        int* __restrict__ npairs, unsigned int* __restrict__ rowmaxU,
                        unsigned long long* __restrict__ rowfinal)
{
    const int r = blockIdx.x;        // 0..1023
    const int t = threadIdx.x;       // 0..63
    if (t == 0) {                    // stream-ordered init (ws poisoned 0xAA each call)
        rowmaxU[r] = 0u;
        rowfinal[r] = 0ull;
        if (r == 0) *npairs = 0;
    }
    const float* src = (r < BATCH) ? p1 : p2;
    const int row = (r < BATCH) ? r : r - BATCH;
    float4 v = ((const float4*)(src + (size_t)row * DIM))[t];
    float sq = v.x*v.x + v.y*v.y + v.z*v.z + v.w*v.w;
    #pragma unroll
    for (int off = 32; off; off >>= 1) sq += __shfl_xor(sq, off, 64);
    sq = fmaxf(sq, 1e-12f);
    float s = rsqrtf(sq);
    s = s * (1.5f - 0.5f * sq * s * s);
    v.x *= s; v.y *= s; v.z *= s; v.w *= s;
    ((float4*)(Pn + (size_t)r * DIM))[t] = v;
    const int k = t * 4;
    PnT[(size_t)(k + 0) * MROWS + r] = v.x;
    PnT[(size_t)(k + 1) * MROWS + r] = v.y;
    PnT[(size_t)(k + 2) * MROWS + r] = v.z;
    PnT[(size_t)(k + 3) * MROWS + r] = v.w;
    short4 b;
    b.x = (short)f2bf(v.x); b.y = (short)f2bf(v.y);
    b.z = (short)f2bf(v.z); b.w = (short)f2bf(v.w);
    ((short4*)Phi)[(size_t)r * (DIM / 4) + t] = b;
    if (r < BATCH) ((float4*)(outq + (size_t)r * DIM))[t] = v;  // new_queue[0:512] = p1n
}

// ---------------- k2: transposed bf16 MFMA filter + fused convert + FIFO copy ----------------
// 512 blocks, one per 128-row queue tile. LDS: Q-tile, 16B chunk (r, c16) at
// r*512 + ((c16 ^ (r & 31)) << 4). mfma(Qfrag, Pfrag): C rows = n (q*4+reg), C cols = m (lr).
__global__ __launch_bounds__(256, 2)
void k2_mfma(const unsigned short* __restrict__ Phi, const float* __restrict__ queue,
             float* __restrict__ outq, float* __restrict__ cand)
{
    __shared__ __align__(16) char Bs[65536];
    const int nt = blockIdx.x;       // 0..511
    const int n0 = nt * 128;
    const int t  = threadIdx.x;
    const int w  = t >> 6, lane = t & 63;
    const int wm = w & 1, wn = w >> 1;
    const int lr = lane & 15, q = lane >> 4;

    // ---- stage: read queue fp32 tile (coalesced), FIFO-copy to outq, cvt bf16 -> swizzled LDS
    {
        const float4* qsrc = (const float4*)(queue + (size_t)n0 * DIM);
        float4* qdst = (float4*)(outq + (size_t)(n0 + BATCH) * DIM);
        #pragma unroll 4
        for (int it = 0; it < 32; ++it) {
            const int L = it * 256 + t;          // 0..8191
            const int r = L >> 6, h = L & 63;
            float4 v = qsrc[(size_t)r * 64 + h];
            if (n0 + r < QUEUE - BATCH) qdst[(size_t)r * 64 + h] = v;
            short4 b;
            b.x = (short)f2bf(v.x); b.y = (short)f2bf(v.y);
            b.z = (short)f2bf(v.z); b.w = (short)f2bf(v.w);
            const int c16 = h >> 1, half = h & 1;
            *(short4*)(Bs + r * 512 + ((c16 ^ (r & 31)) << 4) + half * 8) = b;
        }
    }
    __syncthreads();

    const unsigned short* Pw = Phi + (size_t)(wm * 64 + lr) * DIM + q * 8;

    for (int mt = 0; mt < 8; ++mt) {
        const int m0 = mt * 128;
        f32x4 acc[4][4];                 // [ni][mj]
        #pragma unroll
        for (int i = 0; i < 4; ++i)
            #pragma unroll
            for (int j = 0; j < 4; ++j) acc[i][j] = (f32x4){0.f, 0.f, 0.f, 0.f};

        const unsigned short* Pmt = Pw + (size_t)m0 * DIM;
        #pragma unroll 2
        for (int ks = 0; ks < 8; ++ks) {
            bf16x8 qf[4], pf[4];
            #pragma unroll
            for (int ni = 0; ni < 4; ++ni) {
                const int r = wn * 64 + ni * 16 + lr;
                const int c16 = ks * 4 + q;
                qf[ni] = *(const bf16x8*)(Bs + r * 512 + ((c16 ^ (r & 31)) << 4));
            }
            #pragma unroll
            for (int mj = 0; mj < 4; ++mj)
                pf[mj] = *(const bf16x8*)(Pmt + (size_t)mj * 16 * DIM + ks * 32);
            #pragma unroll
            for (int ni = 0; ni < 4; ++ni)
                #pragma unroll
                for (int mj = 0; mj < 4; ++mj)
                    acc[ni][mj] = __builtin_amdgcn_mfma_f32_16x16x32_bf16(qf[ni], pf[mj], acc[ni][mj], 0, 0, 0);
        }

        // ---- epilogue: per (m, 32-n-group) max. n in-lane (+q), m across 16 lanes.
        #pragma unroll
        for (int mj = 0; mj < 4; ++mj) {
            #pragma unroll
            for (int gl = 0; gl < 2; ++gl) {
                f32x4 va = acc[2 * gl][mj], vb = acc[2 * gl + 1][mj];
                float mx = fmaxf(fmaxf(fmaxf(va[0], va[1]), fmaxf(va[2], va[3])),
                                 fmaxf(fmaxf(vb[0], vb[1]), fmaxf(vb[2], vb[3])));
                mx = fmaxf(mx, __shfl_xor(mx, 16, 64));
                mx = fmaxf(mx, __shfl_xor(mx, 32, 64));
                if (q == 0)
                    cand[(size_t)(nt * 4 + wn * 2 + gl) * MROWS + (m0 + wm * 64 + mj * 16 + lr)] = mx;
            }
        }
    }
}

// ---------------- k2b: per-row max over groups (wide, pipelined) ----------------
// grid = 16 m-chunks x 16 g-chunks = 256 blocks; wave gs scans 32 g's, unrolled.
__global__ void k2b_rowmax(const float* __restrict__ cand, unsigned int* __restrict__ rowmaxU)
{
    const int t  = threadIdx.x;              // 256
    const int ml = t & 63, gs = t >> 6;
    const int mc = blockIdx.x & 15, gc = blockIdx.x >> 4;
    const int m  = mc * 64 + ml;
    const int g0 = gc * 128 + gs * 32;
    float mx = -1e30f;
    #pragma unroll 8
    for (int j = 0; j < 32; ++j)
        mx = fmaxf(mx, cand[(size_t)(g0 + j) * MROWS + m]);
    __shared__ float pm[4][64];
    pm[gs][ml] = mx;
    __syncthreads();
    if (gs == 0) {
        mx = fmaxf(fmaxf(pm[0][ml], pm[1][ml]), fmaxf(pm[2][ml], pm[3][ml]));
        atomicMax(rowmaxU + m, mono_f32(mx));
    }
}

// ---------------- k2c: margin filter -> pair list (wide, pipelined) ----------------
__global__ void k2c_filter(const float* __restrict__ cand, const unsigned int* __restrict__ rowmaxU,
                           unsigned int* __restrict__ pairs, int* __restrict__ npairs)
{
    const int t  = threadIdx.x;              // 256
    const int ml = t & 63, gs = t >> 6;
    const int mc = blockIdx.x & 15, gc = blockIdx.x >> 4;
    const int m  = mc * 64 + ml;
    const int g0 = gc * 128 + gs * 32;
    const float thr = unmono_f32(rowmaxU[m]) - MARGIN;
    #pragma unroll 8
    for (int j = 0; j < 32; ++j) {
        if (cand[(size_t)(g0 + j) * MROWS + m] >= thr) {
            int p = atomicAdd(npairs, 1);
            pairs[p] = ((unsigned int)m << 16) | (unsigned int)(g0 + j);
        }
    }
}

// ---------------- k2d: exact fp32 rescore, one wave per (row,group) ----------------
__global__ __launch_bounds__(256, 4)
void k2d_rescore(const unsigned int* __restrict__ pairs, const int* __restrict__ npairs,
                 const float* __restrict__ Pn, const float* __restrict__ queue,
                 unsigned long long* __restrict__ rowfinal)
{
    const int t = threadIdx.x, w = t >> 6, lane = t & 63;
    const int n = *npairs;
    const int col_l = lane & 31, half = lane >> 5;
    for (int p = blockIdx.x * 4 + w; p < n; p += gridDim.x * 4) {
        const unsigned int pr = pairs[p];
        const int row = pr >> 16, g = pr & 0xffff;
        const int col = g * 32 + col_l;
        const float4* qp = (const float4*)(queue + (size_t)col * DIM + half * 128);
        const float4* pp = (const float4*)(Pn + (size_t)row * DIM + half * 128);
        float4 sv = {0.f, 0.f, 0.f, 0.f};
        #pragma unroll 8
        for (int j = 0; j < 32; ++j) {
            float4 a = pp[j], b = qp[j];
            sv.x = fmaf(a.x, b.x, sv.x); sv.y = fmaf(a.y, b.y, sv.y);
            sv.z = fmaf(a.z, b.z, sv.z); sv.w = fmaf(a.w, b.w, sv.w);
        }
        float s = (sv.x + sv.y) + (sv.z + sv.w);
        s += __shfl_xor(s, 32, 64);                       // combine k-halves
        unsigned long long best = ((unsigned long long)mono_f32(s) << 32)
                                | (unsigned int)(65535 - col);
        #pragma unroll
        for (int off = 1; off <= 16; off <<= 1) {
            unsigned long long o = __shfl_xor(best, off, 64);
            best = best > o ? best : o;
        }
        if (lane == 0) atomicMax(rowfinal + row, best);
    }
}

// ---------------- k3: S1/S2 similarity matrices (8 rows/block, nnidx from rowfinal) --------
__global__ void k3_sim(const unsigned long long* __restrict__ rowfinal,
                       const float* __restrict__ queue,
                       const float* __restrict__ PnT, float* __restrict__ S)
{
    const int rb = blockIdx.x * 8;   // 0..1016 (rows of [nn1;nn2])
    const int tid = threadIdx.x;     // 256
    const int which = (rb < BATCH) ? 0 : 1;
    const int colbase = which ? 0 : BATCH;    // S1 vs p2 (cols 512..1023), S2 vs p1 (0..511)
    __shared__ float nnv[8][DIM];
    #pragma unroll
    for (int j = 0; j < 8; ++j) {
        const int idx = 65535 - (int)(rowfinal[rb + j] & 0xFFFFull);
        nnv[j][tid] = queue[(size_t)idx * DIM + tid];
    }
    __syncthreads();
    float acc0[8], acc1[8];
    #pragma unroll
    for (int j = 0; j < 8; ++j) { acc0[j] = 0.f; acc1[j] = 0.f; }
    for (int k4 = 0; k4 < 64; ++k4) {
        float4 nv[8];
        #pragma unroll
        for (int j = 0; j < 8; ++j) nv[j] = ((const float4*)nnv[j])[k4];
        #pragma unroll
        for (int kk = 0; kk < 4; ++kk) {
            const int k = k4 * 4 + kk;
            const float v0 = PnT[(size_t)k * MROWS + colbase + tid];
            const float v1 = PnT[(size_t)k * MROWS + colbase + tid + 256];
            #pragma unroll
            for (int j = 0; j < 8; ++j) {
                const float nj = ((const float*)&nv[j])[kk];
                acc0[j] = fmaf(nj, v0, acc0[j]);
                acc1[j] = fmaf(nj, v1, acc1[j]);
            }
        }
    }
    const int i0 = rb & (BATCH - 1);
    float* Sout = S + (size_t)which * (BATCH * BATCH);
    #pragma unroll
    for (int j = 0; j < 8; ++j) {
        Sout[(size_t)(i0 + j) * BATCH + tid]       = acc0[j] * 10.0f;
        Sout[(size_t)(i0 + j) * BATCH + tid + 256] = acc1[j] * 10.0f;
    }
}

// ---------------- k4: loss ----------------
__global__ void k4_loss(const float* __restrict__ S, float* __restrict__ loss)
{
    const int r = blockIdx.x;        // 0..2047
    const int tid = threadIdx.x;     // 256
    const int grp = r >> 9;
    const int i = r & 511;
    const float* M = S + (size_t)(grp >> 1) * (BATCH * BATCH);
    float x0, x1;
    if (!(grp & 1)) { x0 = M[(size_t)i * BATCH + tid];  x1 = M[(size_t)i * BATCH + tid + 256]; }
    else            { x0 = M[(size_t)tid * BATCH + i];  x1 = M[(size_t)(tid + 256) * BATCH + i]; }
    const float diag = M[(size_t)i * BATCH + i];
    float mx = fmaxf(x0, x1);
    #pragma unroll
    for (int off = 1; off < 64; off <<= 1) mx = fmaxf(mx, __shfl_xor(mx, off, 64));
    __shared__ float redm[4], reds[4];
    if ((tid & 63) == 0) redm[tid >> 6] = mx;
    __syncthreads();
    mx = fmaxf(fmaxf(redm[0], redm[1]), fmaxf(redm[2], redm[3]));
    float e = __expf(x0 - mx) + __expf(x1 - mx);
    #pragma unroll
    for (int off = 1; off < 64; off <<= 1) e += __shfl_xor(e, off, 64);
    if ((tid & 63) == 0) reds[tid >> 6] = e;
    __syncthreads();
    if (tid == 0)
        loss[r] = mx + logf(reds[0] + reds[1] + reds[2] + reds[3]) - diag;
}

// ---------------- launcher ----------------
extern "C" void kernel_launch(void* const* d_in, const int* in_sizes, int n_in,
                              void* d_out, int out_size, void* d_ws, size_t ws_size,
                              hipStream_t stream)
{
    const float* p1    = (const float*)d_in[0];
    const float* p2    = (const float*)d_in[1];
    const float* queue = (const float*)d_in[2];
    float* out  = (float*)d_out;
    float* loss = out;
    float* outq = out + 4 * BATCH;

    // Workspace (~20.6 MB)
    char* w = (char*)d_ws;
    float* cand = (float*)w;                               w += (size_t)NGRP * MROWS * 4;   // 8 MB [g][m]
    unsigned long long* rowfinal = (unsigned long long*)w; w += MROWS * 8;
    unsigned int* rowmaxU = (unsigned int*)w;              w += MROWS * 4;
    float* Pn  = (float*)w;                                w += (size_t)MROWS * DIM * 4;    // 1 MB
    float* PnT = (float*)w;                                w += (size_t)MROWS * DIM * 4;    // 1 MB
    unsigned short* Phi = (unsigned short*)w;              w += (size_t)MROWS * DIM * 2;    // 0.5 MB
    float* S = (float*)w;                                  w += (size_t)2 * BATCH * BATCH * 4; // 2 MB
    unsigned int* pairs = (unsigned int*)w;                w += (size_t)NGRP * MROWS * 4;   // 8 MB (worst case)
    int* npairs = (int*)w;

    hipLaunchKernelGGL(k1_norm,     dim3(MROWS), dim3(64),  0, stream, p1, p2, Pn, PnT, Phi, outq,
                       npairs, rowmaxU, rowfinal);
    hipLaunchKernelGGL(k2_mfma,     dim3(QUEUE / 128), dim3(256), 0, stream, Phi, queue, outq, cand);
    hipLaunchKernelGGL(k2b_rowmax,  dim3(256),   dim3(256), 0, stream, cand, rowmaxU);
    hipLaunchKernelGGL(k2c_filter,  dim3(256),   dim3(256), 0, stream, cand, rowmaxU, pairs, npairs);
    hipLaunchKernelGGL(k2d_rescore, dim3(512),   dim3(256), 0, stream, pairs, npairs, Pn, queue, rowfinal);
    hipLaunchKernelGGL(k3_sim,      dim3(MROWS / 8), dim3(256), 0, stream, rowfinal, queue, PnT, S);
    hipLaunchKernelGGL(k4_loss,     dim3(4 * BATCH), dim3(256), 0, stream, S, loss);
}